// Round 1
// baseline (594.307 us; speedup 1.0000x reference)
//
#include <hip/hip_runtime.h>
#include <cmath>

#define ALPHA 1.702f
#define LIMIT 7.0f

constexpr int B = 2, S = 1024, H = 768, E = 8, I = 768;
constexpr int T = B * S;          // 2048 tokens
constexpr int TWO_I = 2 * I;      // 1536
constexpr int NROWS = T * 2;      // 4096 (token, expert) entries, exactly 2 per token

// ---------------------------------------------------------------------------
// Router: 1 wave per token. logits = x @ Wr + br, top-2, softmax over the 2.
// ---------------------------------------------------------------------------
__global__ __launch_bounds__(64) void router_kernel(
    const float* __restrict__ x, const float* __restrict__ Wr,
    const float* __restrict__ br, int* __restrict__ topk_idx,
    float* __restrict__ topk_w) {
  int t = blockIdx.x;
  int lane = threadIdx.x;  // 0..63
  const float* xr = x + (size_t)t * H;
  float acc[E];
#pragma unroll
  for (int e = 0; e < E; e++) acc[e] = 0.0f;
  for (int h = lane; h < H; h += 64) {
    float xv = xr[h];
    const float* wrow = Wr + (size_t)h * E;
#pragma unroll
    for (int e = 0; e < E; e++) acc[e] += xv * wrow[e];
  }
#pragma unroll
  for (int e = 0; e < E; e++) {
    float v = acc[e];
    for (int off = 32; off > 0; off >>= 1) v += __shfl_down(v, off, 64);
    acc[e] = v;
  }
  if (lane == 0) {
    float logits[E];
#pragma unroll
    for (int e = 0; e < E; e++) logits[e] = acc[e] + br[e];
    // top-1: strict > so first index wins ties (jax.lax.top_k semantics)
    int i0 = 0;
    float v0 = logits[0];
#pragma unroll
    for (int e = 1; e < E; e++)
      if (logits[e] > v0) { v0 = logits[e]; i0 = e; }
    int i1 = -1;
    float v1 = -INFINITY;
#pragma unroll
    for (int e = 0; e < E; e++) {
      if (e == i0) continue;
      if (logits[e] > v1) { v1 = logits[e]; i1 = e; }
    }
    float s1 = __expf(v1 - v0);  // exp of (second - max)
    float denom = 1.0f + s1;
    topk_idx[t * 2 + 0] = i0;
    topk_idx[t * 2 + 1] = i1;
    topk_w[t * 2 + 0] = 1.0f / denom;
    topk_w[t * 2 + 1] = s1 / denom;
  }
}

// ---------------------------------------------------------------------------
// Build per-expert contiguous row ranges. Single block; 4096 entries.
// ---------------------------------------------------------------------------
__global__ __launch_bounds__(256) void build_assign(
    const int* __restrict__ topk_idx, const float* __restrict__ topk_w,
    int* __restrict__ e_start, int* __restrict__ e_count,
    int* __restrict__ row_token, float* __restrict__ row_w) {
  __shared__ int cnt[E], base[E], cur[E];
  int tid = threadIdx.x;
  if (tid < E) cnt[tid] = 0;
  __syncthreads();
  for (int i = tid; i < NROWS; i += blockDim.x) atomicAdd(&cnt[topk_idx[i]], 1);
  __syncthreads();
  if (tid == 0) {
    int s = 0;
    for (int e = 0; e < E; e++) { base[e] = s; s += cnt[e]; }
  }
  __syncthreads();
  if (tid < E) {
    e_start[tid] = base[tid];
    e_count[tid] = cnt[tid];
    cur[tid] = 0;
  }
  __syncthreads();
  for (int i = tid; i < NROWS; i += blockDim.x) {
    int e = topk_idx[i];
    int pos = atomicAdd(&cur[e], 1);
    int row = base[e] + pos;
    row_token[row] = i >> 1;
    row_w[row] = topk_w[i];
  }
}

// ---------------------------------------------------------------------------
// GEMM1: gu[row, f] = sum_h X[token(row), h] * Wgu[e, h, f] + bgu[e, f]
// 64x64 tile, BK=16, 256 threads, 4x4 per thread. fp32.
// ---------------------------------------------------------------------------
__global__ __launch_bounds__(256) void gemm_gu(
    const float* __restrict__ x, const float* __restrict__ Wgu,
    const float* __restrict__ bgu, const int* __restrict__ e_start,
    const int* __restrict__ e_count, const int* __restrict__ row_token,
    float* __restrict__ gu) {
  int e = blockIdx.z;
  int cnt = e_count[e];
  int m0 = blockIdx.y * 64;
  if (m0 >= cnt) return;
  int n0 = blockIdx.x * 64;
  int start = e_start[e];
  const float* W = Wgu + (size_t)e * H * TWO_I;
  const float* bias = bgu + (size_t)e * TWO_I;

  __shared__ float As[16][64 + 1];  // [k][m]
  __shared__ float Bs[16][64 + 1];  // [k][n]
  __shared__ int tok[64];

  int tid = threadIdx.x;
  if (tid < 64) {
    int m = m0 + tid;
    tok[tid] = (m < cnt) ? row_token[start + m] : -1;
  }
  __syncthreads();

  int tx = tid & 15;   // n-direction
  int ty = tid >> 4;   // m-direction
  float acc[4][4] = {{0}};

  for (int k0 = 0; k0 < H; k0 += 16) {
#pragma unroll
    for (int r = 0; r < 4; r++) {
      int l = tid + r * 256;  // 0..1023 over 64m x 16k
      int m = l >> 4;
      int k = l & 15;
      int t = tok[m];
      As[k][m] = (t >= 0) ? x[(size_t)t * H + k0 + k] : 0.0f;
    }
#pragma unroll
    for (int r = 0; r < 4; r++) {
      int l = tid + r * 256;  // 16k x 64n
      int k = l >> 6;
      int n = l & 63;
      Bs[k][n] = W[(size_t)(k0 + k) * TWO_I + n0 + n];
    }
    __syncthreads();
#pragma unroll
    for (int k = 0; k < 16; k++) {
      float a[4], b[4];
#pragma unroll
      for (int i = 0; i < 4; i++) a[i] = As[k][ty * 4 + i];
#pragma unroll
      for (int j = 0; j < 4; j++) b[j] = Bs[k][tx * 4 + j];
#pragma unroll
      for (int i = 0; i < 4; i++)
#pragma unroll
        for (int j = 0; j < 4; j++) acc[i][j] += a[i] * b[j];
    }
    __syncthreads();
  }
#pragma unroll
  for (int i = 0; i < 4; i++) {
    int m = m0 + ty * 4 + i;
    if (m >= cnt) continue;
    size_t row = (size_t)(start + m) * TWO_I;
#pragma unroll
    for (int j = 0; j < 4; j++) {
      int n = n0 + tx * 4 + j;
      gu[row + n] = acc[i][j] + bias[n];
    }
  }
}

// ---------------------------------------------------------------------------
// GEMM2: down[row, h] = sum_i act(gu[row, i], gu[row, I+i]) * Wd[e, i, h] + bd
// Activation fused into the A-tile stage. Weighted atomic scatter to output.
// ---------------------------------------------------------------------------
__global__ __launch_bounds__(256) void gemm_down(
    const float* __restrict__ gu, const float* __restrict__ Wd,
    const float* __restrict__ bd, const int* __restrict__ e_start,
    const int* __restrict__ e_count, const int* __restrict__ row_token,
    const float* __restrict__ row_w, float* __restrict__ out) {
  int e = blockIdx.z;
  int cnt = e_count[e];
  int m0 = blockIdx.y * 64;
  if (m0 >= cnt) return;
  int n0 = blockIdx.x * 64;
  int start = e_start[e];
  const float* W = Wd + (size_t)e * I * H;
  const float* bias = bd + (size_t)e * H;

  __shared__ float As[16][64 + 1];
  __shared__ float Bs[16][64 + 1];

  int tid = threadIdx.x;
  int tx = tid & 15;
  int ty = tid >> 4;
  float acc[4][4] = {{0}};

  for (int k0 = 0; k0 < I; k0 += 16) {
#pragma unroll
    for (int r = 0; r < 4; r++) {
      int l = tid + r * 256;
      int m = l >> 4;
      int k = l & 15;
      int gm = m0 + m;
      float v = 0.0f;
      if (gm < cnt) {
        size_t row = (size_t)(start + gm) * TWO_I;
        float g = gu[row + k0 + k];
        float u = gu[row + I + k0 + k];
        g = fminf(g, LIMIT);
        u = fmaxf(fminf(u, LIMIT), -LIMIT);
        float glu = g / (1.0f + __expf(-ALPHA * g));  // g * sigmoid(ALPHA*g)
        v = (u + 1.0f) * glu;
      }
      As[k][m] = v;
    }
#pragma unroll
    for (int r = 0; r < 4; r++) {
      int l = tid + r * 256;
      int k = l >> 6;
      int n = l & 63;
      Bs[k][n] = W[(size_t)(k0 + k) * H + n0 + n];
    }
    __syncthreads();
#pragma unroll
    for (int k = 0; k < 16; k++) {
      float a[4], b[4];
#pragma unroll
      for (int i = 0; i < 4; i++) a[i] = As[k][ty * 4 + i];
#pragma unroll
      for (int j = 0; j < 4; j++) b[j] = Bs[k][tx * 4 + j];
#pragma unroll
      for (int i = 0; i < 4; i++)
#pragma unroll
        for (int j = 0; j < 4; j++) acc[i][j] += a[i] * b[j];
    }
    __syncthreads();
  }
#pragma unroll
  for (int i = 0; i < 4; i++) {
    int m = m0 + ty * 4 + i;
    if (m >= cnt) continue;
    int gr = start + m;
    int t = row_token[gr];
    float w = row_w[gr];
#pragma unroll
    for (int j = 0; j < 4; j++) {
      int n = n0 + tx * 4 + j;
      atomicAdd(&out[(size_t)t * H + n], w * (acc[i][j] + bias[n]));
    }
  }
}

// ---------------------------------------------------------------------------
extern "C" void kernel_launch(void* const* d_in, const int* in_sizes, int n_in,
                              void* d_out, int out_size, void* d_ws,
                              size_t ws_size, hipStream_t stream) {
  const float* x   = (const float*)d_in[0];
  const float* Wr  = (const float*)d_in[1];
  const float* br  = (const float*)d_in[2];
  const float* Wgu = (const float*)d_in[3];
  const float* bgu = (const float*)d_in[4];
  const float* Wd  = (const float*)d_in[5];
  const float* bd  = (const float*)d_in[6];
  float* out = (float*)d_out;

  // workspace layout
  char* w = (char*)d_ws;
  int* topk_idx = (int*)w;   w += (size_t)T * 2 * sizeof(int);
  float* topk_w = (float*)w; w += (size_t)T * 2 * sizeof(float);
  int* e_start = (int*)w;    w += 16 * sizeof(int);
  int* e_count = (int*)w;    w += 16 * sizeof(int);
  int* row_token = (int*)w;  w += (size_t)NROWS * sizeof(int);
  float* row_w = (float*)w;  w += (size_t)NROWS * sizeof(float);
  float* gu = (float*)w;     // NROWS * TWO_I floats = 25.2 MB

  hipMemsetAsync(d_out, 0, (size_t)out_size * sizeof(float), stream);

  router_kernel<<<T, 64, 0, stream>>>(x, Wr, br, topk_idx, topk_w);
  build_assign<<<1, 256, 0, stream>>>(topk_idx, topk_w, e_start, e_count,
                                      row_token, row_w);
  gemm_gu<<<dim3(TWO_I / 64, (T * 2 + 63) / 64, E), 256, 0, stream>>>(
      x, Wgu, bgu, e_start, e_count, row_token, gu);
  gemm_down<<<dim3(H / 64, (T * 2 + 63) / 64, E), 256, 0, stream>>>(
      gu, Wd, bd, e_start, e_count, row_token, row_w, out);
}

// Round 2
// 204.007 us; speedup vs baseline: 2.9132x; 2.9132x over previous
//
#include <hip/hip_runtime.h>
#include <hip/hip_bf16.h>
#include <cmath>

#define ALPHA 1.702f
#define LIMIT 7.0f

constexpr int B = 2, S = 1024, H = 768, E = 8, I = 768;
constexpr int T = B * S;          // 2048 tokens
constexpr int TWO_I = 2 * I;      // 1536
constexpr int NROWS = T * 2;      // 4096 (token, expert) rows

typedef __attribute__((ext_vector_type(8))) short short8;
typedef __attribute__((ext_vector_type(4))) float floatx4;

__device__ __forceinline__ unsigned short f2bf(float v) {
  __hip_bfloat16 h = __float2bfloat16(v);
  return *reinterpret_cast<unsigned short*>(&h);
}

// ---------------------------------------------------------------------------
// Router: 1 wave per token. Also casts x row to bf16 (fused).
// ---------------------------------------------------------------------------
__global__ __launch_bounds__(64) void router_kernel(
    const float* __restrict__ x, const float* __restrict__ Wr,
    const float* __restrict__ br, int* __restrict__ topk_idx,
    float* __restrict__ topk_w, unsigned short* __restrict__ xb) {
  int t = blockIdx.x;
  int lane = threadIdx.x;  // 0..63
  const float* xr = x + (size_t)t * H;
  unsigned short* xbr = xb + (size_t)t * H;
  float acc[E];
#pragma unroll
  for (int e = 0; e < E; e++) acc[e] = 0.0f;
  for (int h = lane; h < H; h += 64) {
    float xv = xr[h];
    xbr[h] = f2bf(xv);
    const float* wrow = Wr + (size_t)h * E;
#pragma unroll
    for (int e = 0; e < E; e++) acc[e] += xv * wrow[e];
  }
#pragma unroll
  for (int e = 0; e < E; e++) {
    float v = acc[e];
    for (int off = 32; off > 0; off >>= 1) v += __shfl_down(v, off, 64);
    acc[e] = v;
  }
  if (lane == 0) {
    float logits[E];
#pragma unroll
    for (int e = 0; e < E; e++) logits[e] = acc[e] + br[e];
    int i0 = 0;
    float v0 = logits[0];
#pragma unroll
    for (int e = 1; e < E; e++)
      if (logits[e] > v0) { v0 = logits[e]; i0 = e; }
    int i1 = -1;
    float v1 = -INFINITY;
#pragma unroll
    for (int e = 0; e < E; e++) {
      if (e == i0) continue;
      if (logits[e] > v1) { v1 = logits[e]; i1 = e; }
    }
    float s1 = __expf(v1 - v0);
    float denom = 1.0f + s1;
    topk_idx[t * 2 + 0] = i0;
    topk_idx[t * 2 + 1] = i1;
    topk_w[t * 2 + 0] = 1.0f / denom;
    topk_w[t * 2 + 1] = s1 / denom;
  }
}

// ---------------------------------------------------------------------------
// Per-expert contiguous row ranges. Single block.
// ---------------------------------------------------------------------------
__global__ __launch_bounds__(256) void build_assign(
    const int* __restrict__ topk_idx, const float* __restrict__ topk_w,
    int* __restrict__ e_start, int* __restrict__ e_count,
    int* __restrict__ row_token, float* __restrict__ row_w) {
  __shared__ int cnt[E], base[E], cur[E];
  int tid = threadIdx.x;
  if (tid < E) cnt[tid] = 0;
  __syncthreads();
  for (int i = tid; i < NROWS; i += blockDim.x) atomicAdd(&cnt[topk_idx[i]], 1);
  __syncthreads();
  if (tid == 0) {
    int s = 0;
    for (int e = 0; e < E; e++) { base[e] = s; s += cnt[e]; }
  }
  __syncthreads();
  if (tid < E) {
    e_start[tid] = base[tid];
    e_count[tid] = cnt[tid];
    cur[tid] = 0;
  }
  __syncthreads();
  for (int i = tid; i < NROWS; i += blockDim.x) {
    int e = topk_idx[i];
    int pos = atomicAdd(&cur[e], 1);
    int row = base[e] + pos;
    row_token[row] = i >> 1;
    row_w[row] = topk_w[i];
  }
}

// ---------------------------------------------------------------------------
// Transpose + cast: in [z][K][N] fp32 -> out [z][N][K] bf16. 32x32 tiles.
// ---------------------------------------------------------------------------
__global__ __launch_bounds__(256) void transpose_bf16(
    const float* __restrict__ in, unsigned short* __restrict__ out,
    int K, int N) {
  int z = blockIdx.z;
  const float* inz = in + (size_t)z * K * N;
  unsigned short* outz = out + (size_t)z * K * N;
  __shared__ float tile[32][33];
  int n0 = blockIdx.x * 32, k0 = blockIdx.y * 32;
  int tx = threadIdx.x & 31, ty = threadIdx.x >> 5;
#pragma unroll
  for (int r = 0; r < 4; r++)
    tile[ty + 8 * r][tx] = inz[(size_t)(k0 + ty + 8 * r) * N + n0 + tx];
  __syncthreads();
#pragma unroll
  for (int r = 0; r < 4; r++)
    outz[(size_t)(n0 + ty + 8 * r) * K + k0 + tx] = f2bf(tile[tx][ty + 8 * r]);
}

// ---------------------------------------------------------------------------
// GEMM1 (MFMA): act[row, f] for f in [n0,n0+64) computed from gate & up pair.
// Tile: 128m x 64n (gate) + 128m x 64n (up), K=768, BK=32. 4 waves of 64x32.
// Epilogue: clip + swiglu, store activated bf16.
// ---------------------------------------------------------------------------
__global__ __launch_bounds__(256) void gemm_gu_mfma(
    const unsigned short* __restrict__ xb, const unsigned short* __restrict__ Wgt,
    const float* __restrict__ bgu, const int* __restrict__ e_start,
    const int* __restrict__ e_count, const int* __restrict__ row_token,
    unsigned short* __restrict__ act) {
  int e = blockIdx.z;
  int cnt = e_count[e];
  int m0 = blockIdx.y * 128;
  if (m0 >= cnt) return;
  int n0 = blockIdx.x * 64;
  int start = e_start[e];
  const unsigned short* Wg = Wgt + (size_t)e * TWO_I * H;  // [f][h]
  const float* bias = bgu + (size_t)e * TWO_I;

  __shared__ short As[128][40];
  __shared__ short Bg[64][40];
  __shared__ short Bu[64][40];
  __shared__ int tok[128];

  int tid = threadIdx.x;
  if (tid < 128) {
    int m = m0 + tid;
    tok[tid] = row_token[start + ((m < cnt) ? m : (cnt - 1))];
  }
  __syncthreads();

  int lane = tid & 63;
  int wave = tid >> 6;
  int quad = lane >> 4;
  int lrow = lane & 15;
  int wm = (wave >> 1) * 64;  // 0 / 64
  int wn = (wave & 1) * 32;   // 0 / 32

  floatx4 accg[4][2], accu[4][2];
#pragma unroll
  for (int i = 0; i < 4; i++)
#pragma unroll
    for (int j = 0; j < 2; j++) {
      accg[i][j] = floatx4{0.f, 0.f, 0.f, 0.f};
      accu[i][j] = floatx4{0.f, 0.f, 0.f, 0.f};
    }

  int nB = tid >> 2, chB = tid & 3;  // B staging: 64 rows x 4 chunks

  for (int k0 = 0; k0 < H; k0 += 32) {
#pragma unroll
    for (int r = 0; r < 2; r++) {
      int idx = tid + r * 256;
      int m = idx >> 2, ch = idx & 3;
      uint4 v = *(const uint4*)(xb + (size_t)tok[m] * H + k0 + ch * 8);
      *(uint4*)(&As[m][ch * 8]) = v;
    }
    *(uint4*)(&Bg[nB][chB * 8]) =
        *(const uint4*)(Wg + (size_t)(n0 + nB) * H + k0 + chB * 8);
    *(uint4*)(&Bu[nB][chB * 8]) =
        *(const uint4*)(Wg + (size_t)(I + n0 + nB) * H + k0 + chB * 8);
    __syncthreads();

    short8 a[4], bg[2], bu[2];
#pragma unroll
    for (int ti = 0; ti < 4; ti++)
      a[ti] = *(const short8*)(&As[wm + ti * 16 + lrow][quad * 8]);
#pragma unroll
    for (int tj = 0; tj < 2; tj++) {
      bg[tj] = *(const short8*)(&Bg[wn + tj * 16 + lrow][quad * 8]);
      bu[tj] = *(const short8*)(&Bu[wn + tj * 16 + lrow][quad * 8]);
    }
#pragma unroll
    for (int ti = 0; ti < 4; ti++)
#pragma unroll
      for (int tj = 0; tj < 2; tj++) {
        accg[ti][tj] = __builtin_amdgcn_mfma_f32_16x16x32_bf16(
            a[ti], bg[tj], accg[ti][tj], 0, 0, 0);
        accu[ti][tj] = __builtin_amdgcn_mfma_f32_16x16x32_bf16(
            a[ti], bu[tj], accu[ti][tj], 0, 0, 0);
      }
    __syncthreads();
  }

#pragma unroll
  for (int ti = 0; ti < 4; ti++) {
#pragma unroll
    for (int tj = 0; tj < 2; tj++) {
      int ncol = n0 + wn + tj * 16 + lrow;
      float bgv = bias[ncol];
      float buv = bias[I + ncol];
#pragma unroll
      for (int r = 0; r < 4; r++) {
        int m = m0 + wm + ti * 16 + quad * 4 + r;
        if (m < cnt) {
          float g = accg[ti][tj][r] + bgv;
          float u = accu[ti][tj][r] + buv;
          g = fminf(g, LIMIT);
          u = fmaxf(fminf(u, LIMIT), -LIMIT);
          float glu = g / (1.0f + __expf(-ALPHA * g));
          act[(size_t)(start + m) * I + ncol] = f2bf((u + 1.0f) * glu);
        }
      }
    }
  }
}

// ---------------------------------------------------------------------------
// GEMM2 (MFMA): down = act @ Wd[e] (+bd), weighted atomic scatter to out.
// Tile 128m x 64n, K=768, BK=32.
// ---------------------------------------------------------------------------
__global__ __launch_bounds__(256) void gemm_down_mfma(
    const unsigned short* __restrict__ act, const unsigned short* __restrict__ Wdt,
    const float* __restrict__ bd, const int* __restrict__ e_start,
    const int* __restrict__ e_count, const int* __restrict__ row_token,
    const float* __restrict__ row_w, float* __restrict__ out) {
  int e = blockIdx.z;
  int cnt = e_count[e];
  int m0 = blockIdx.y * 128;
  if (m0 >= cnt) return;
  int n0 = blockIdx.x * 64;
  int start = e_start[e];
  const unsigned short* Wd = Wdt + (size_t)e * H * I;  // [h][i]
  const float* bias = bd + (size_t)e * H;

  __shared__ short As[128][40];
  __shared__ short Bs[64][40];
  __shared__ int tok[128];
  __shared__ float wts[128];

  int tid = threadIdx.x;
  if (tid < 128) {
    int m = m0 + tid;
    int mm = (m < cnt) ? m : (cnt - 1);
    tok[tid] = row_token[start + mm];
    wts[tid] = row_w[start + mm];
  }
  __syncthreads();

  int lane = tid & 63;
  int wave = tid >> 6;
  int quad = lane >> 4;
  int lrow = lane & 15;
  int wm = (wave >> 1) * 64;
  int wn = (wave & 1) * 32;

  floatx4 acc[4][2];
#pragma unroll
  for (int i = 0; i < 4; i++)
#pragma unroll
    for (int j = 0; j < 2; j++) acc[i][j] = floatx4{0.f, 0.f, 0.f, 0.f};

  int nB = tid >> 2, chB = tid & 3;

  for (int k0 = 0; k0 < I; k0 += 32) {
#pragma unroll
    for (int r = 0; r < 2; r++) {
      int idx = tid + r * 256;
      int m = idx >> 2, ch = idx & 3;
      int gm = m0 + m;
      int mm = (gm < cnt) ? gm : (cnt - 1);
      uint4 v = *(const uint4*)(act + (size_t)(start + mm) * I + k0 + ch * 8);
      *(uint4*)(&As[m][ch * 8]) = v;
    }
    *(uint4*)(&Bs[nB][chB * 8]) =
        *(const uint4*)(Wd + (size_t)(n0 + nB) * I + k0 + chB * 8);
    __syncthreads();

    short8 a[4], b[2];
#pragma unroll
    for (int ti = 0; ti < 4; ti++)
      a[ti] = *(const short8*)(&As[wm + ti * 16 + lrow][quad * 8]);
#pragma unroll
    for (int tj = 0; tj < 2; tj++)
      b[tj] = *(const short8*)(&Bs[wn + tj * 16 + lrow][quad * 8]);
#pragma unroll
    for (int ti = 0; ti < 4; ti++)
#pragma unroll
      for (int tj = 0; tj < 2; tj++)
        acc[ti][tj] = __builtin_amdgcn_mfma_f32_16x16x32_bf16(
            a[ti], b[tj], acc[ti][tj], 0, 0, 0);
    __syncthreads();
  }

#pragma unroll
  for (int ti = 0; ti < 4; ti++) {
#pragma unroll
    for (int tj = 0; tj < 2; tj++) {
      int ncol = n0 + wn + tj * 16 + lrow;
      float bdv = bias[ncol];
#pragma unroll
      for (int r = 0; r < 4; r++) {
        int ml = wm + ti * 16 + quad * 4 + r;
        int m = m0 + ml;
        if (m < cnt) {
          int t = tok[ml];
          float w = wts[ml];
          atomicAdd(&out[(size_t)t * H + ncol], w * (acc[ti][tj][r] + bdv));
        }
      }
    }
  }
}

// ---------------------------------------------------------------------------
extern "C" void kernel_launch(void* const* d_in, const int* in_sizes, int n_in,
                              void* d_out, int out_size, void* d_ws,
                              size_t ws_size, hipStream_t stream) {
  const float* x   = (const float*)d_in[0];
  const float* Wr  = (const float*)d_in[1];
  const float* br  = (const float*)d_in[2];
  const float* Wgu = (const float*)d_in[3];
  const float* bgu = (const float*)d_in[4];
  const float* Wd  = (const float*)d_in[5];
  const float* bd  = (const float*)d_in[6];
  float* out = (float*)d_out;

  // workspace layout (all chunks 16B-aligned)
  char* w = (char*)d_ws;
  int* topk_idx = (int*)w;   w += (size_t)T * 2 * sizeof(int);
  float* topk_w = (float*)w; w += (size_t)T * 2 * sizeof(float);
  int* e_start = (int*)w;    w += 16 * sizeof(int);
  int* e_count = (int*)w;    w += 16 * sizeof(int);
  int* row_token = (int*)w;  w += (size_t)NROWS * sizeof(int);
  float* row_w = (float*)w;  w += (size_t)NROWS * sizeof(float);
  unsigned short* xb  = (unsigned short*)w; w += (size_t)T * H * 2;        // 3.1 MB
  unsigned short* Wgt = (unsigned short*)w; w += (size_t)E * TWO_I * H * 2; // 18.9 MB
  unsigned short* Wdt = (unsigned short*)w; w += (size_t)E * H * I * 2;     // 9.4 MB
  unsigned short* act = (unsigned short*)w; w += (size_t)NROWS * I * 2;     // 6.3 MB

  hipMemsetAsync(d_out, 0, (size_t)out_size * sizeof(float), stream);

  router_kernel<<<T, 64, 0, stream>>>(x, Wr, br, topk_idx, topk_w, xb);
  build_assign<<<1, 256, 0, stream>>>(topk_idx, topk_w, e_start, e_count,
                                      row_token, row_w);
  transpose_bf16<<<dim3(TWO_I / 32, H / 32, E), 256, 0, stream>>>(Wgu, Wgt, H,
                                                                  TWO_I);
  transpose_bf16<<<dim3(H / 32, I / 32, E), 256, 0, stream>>>(Wd, Wdt, I, H);
  gemm_gu_mfma<<<dim3(I / 64, 32, E), 256, 0, stream>>>(
      xb, Wgt, bgu, e_start, e_count, row_token, act);
  gemm_down_mfma<<<dim3(H / 64, 32, E), 256, 0, stream>>>(
      act, Wdt, bd, e_start, e_count, row_token, row_w, out);
}

// Round 3
// 188.867 us; speedup vs baseline: 3.1467x; 1.0802x over previous
//
#include <hip/hip_runtime.h>
#include <hip/hip_bf16.h>
#include <cmath>

#define ALPHA 1.702f
#define LIMIT 7.0f

constexpr int B = 2, S = 1024, H = 768, E = 8, I = 768;
constexpr int T = B * S;          // 2048 tokens
constexpr int TWO_I = 2 * I;      // 1536
constexpr int NROWS = T * 2;      // 4096 (token, expert) rows

typedef __attribute__((ext_vector_type(8))) short short8;
typedef __attribute__((ext_vector_type(4))) float floatx4;

__device__ __forceinline__ unsigned short f2bf(float v) {
  __hip_bfloat16 h = __float2bfloat16(v);
  return *reinterpret_cast<unsigned short*>(&h);
}

// async global->LDS, 16B per lane. LDS dst is wave-uniform base + lane*16.
__device__ __forceinline__ void g2l16(const void* g, void* l) {
  __builtin_amdgcn_global_load_lds(
      (const __attribute__((address_space(1))) void*)g,
      (__attribute__((address_space(3))) void*)l, 16, 0, 0);
}

// ---------------------------------------------------------------------------
// Router: 1 wave per token. Also casts x row to bf16 (fused).
// ---------------------------------------------------------------------------
__global__ __launch_bounds__(64) void router_kernel(
    const float* __restrict__ x, const float* __restrict__ Wr,
    const float* __restrict__ br, int* __restrict__ topk_idx,
    float* __restrict__ topk_w, unsigned short* __restrict__ xb) {
  int t = blockIdx.x;
  int lane = threadIdx.x;  // 0..63
  const float* xr = x + (size_t)t * H;
  unsigned short* xbr = xb + (size_t)t * H;
  float acc[E];
#pragma unroll
  for (int e = 0; e < E; e++) acc[e] = 0.0f;
  for (int h = lane; h < H; h += 64) {
    float xv = xr[h];
    xbr[h] = f2bf(xv);
    const float* wrow = Wr + (size_t)h * E;
#pragma unroll
    for (int e = 0; e < E; e++) acc[e] += xv * wrow[e];
  }
#pragma unroll
  for (int e = 0; e < E; e++) {
    float v = acc[e];
    for (int off = 32; off > 0; off >>= 1) v += __shfl_down(v, off, 64);
    acc[e] = v;
  }
  if (lane == 0) {
    float logits[E];
#pragma unroll
    for (int e = 0; e < E; e++) logits[e] = acc[e] + br[e];
    int i0 = 0;
    float v0 = logits[0];
#pragma unroll
    for (int e = 1; e < E; e++)
      if (logits[e] > v0) { v0 = logits[e]; i0 = e; }
    int i1 = -1;
    float v1 = -INFINITY;
#pragma unroll
    for (int e = 0; e < E; e++) {
      if (e == i0) continue;
      if (logits[e] > v1) { v1 = logits[e]; i1 = e; }
    }
    float s1 = __expf(v1 - v0);
    float denom = 1.0f + s1;
    topk_idx[t * 2 + 0] = i0;
    topk_idx[t * 2 + 1] = i1;
    topk_w[t * 2 + 0] = 1.0f / denom;
    topk_w[t * 2 + 1] = s1 / denom;
  }
}

// ---------------------------------------------------------------------------
// Per-expert contiguous row ranges. Single block.
// ---------------------------------------------------------------------------
__global__ __launch_bounds__(256) void build_assign(
    const int* __restrict__ topk_idx, const float* __restrict__ topk_w,
    int* __restrict__ e_start, int* __restrict__ e_count,
    int* __restrict__ row_token, float* __restrict__ row_w) {
  __shared__ int cnt[E], base[E], cur[E];
  int tid = threadIdx.x;
  if (tid < E) cnt[tid] = 0;
  __syncthreads();
  for (int i = tid; i < NROWS; i += blockDim.x) atomicAdd(&cnt[topk_idx[i]], 1);
  __syncthreads();
  if (tid == 0) {
    int s = 0;
    for (int e = 0; e < E; e++) { base[e] = s; s += cnt[e]; }
  }
  __syncthreads();
  if (tid < E) {
    e_start[tid] = base[tid];
    e_count[tid] = cnt[tid];
    cur[tid] = 0;
  }
  __syncthreads();
  for (int i = tid; i < NROWS; i += blockDim.x) {
    int e = topk_idx[i];
    int pos = atomicAdd(&cur[e], 1);
    int row = base[e] + pos;
    row_token[row] = i >> 1;
    row_w[row] = topk_w[i];
  }
}

// ---------------------------------------------------------------------------
// Transpose + cast: in [z][K][N] fp32 -> out [z][N][K] bf16. 32x32 tiles.
// ---------------------------------------------------------------------------
__global__ __launch_bounds__(256) void transpose_bf16(
    const float* __restrict__ in, unsigned short* __restrict__ out,
    int K, int N) {
  int z = blockIdx.z;
  const float* inz = in + (size_t)z * K * N;
  unsigned short* outz = out + (size_t)z * K * N;
  __shared__ float tile[32][33];
  int n0 = blockIdx.x * 32, k0 = blockIdx.y * 32;
  int tx = threadIdx.x & 31, ty = threadIdx.x >> 5;
#pragma unroll
  for (int r = 0; r < 4; r++)
    tile[ty + 8 * r][tx] = inz[(size_t)(k0 + ty + 8 * r) * N + n0 + tx];
  __syncthreads();
#pragma unroll
  for (int r = 0; r < 4; r++)
    outz[(size_t)(n0 + ty + 8 * r) * K + k0 + tx] = f2bf(tile[tx][ty + 8 * r]);
}

// ---------------------------------------------------------------------------
// GEMM1 (MFMA + global_load_lds): 128m x 64n tile, gate & up together.
// K=768, BK=32. Unpadded LDS [row][32 shorts]. Epilogue: clip+swiglu, bf16.
// ---------------------------------------------------------------------------
__global__ __launch_bounds__(256) void gemm_gu_mfma(
    const unsigned short* __restrict__ xb, const unsigned short* __restrict__ Wgt,
    const float* __restrict__ bgu, const int* __restrict__ e_start,
    const int* __restrict__ e_count, const int* __restrict__ row_token,
    unsigned short* __restrict__ act) {
  int e = blockIdx.z;
  int cnt = e_count[e];
  int m0 = blockIdx.y * 128;
  if (m0 >= cnt) return;
  int n0 = blockIdx.x * 64;
  int start = e_start[e];
  const unsigned short* Wg = Wgt + (size_t)e * TWO_I * H;  // [f][h]
  const float* bias = bgu + (size_t)e * TWO_I;

  __shared__ short As[128 * 32];  // 8 KB, unpadded (lane-order DMA layout)
  __shared__ short Bg[64 * 32];   // 4 KB
  __shared__ short Bu[64 * 32];   // 4 KB
  __shared__ int tok[128];

  int tid = threadIdx.x;
  if (tid < 128) {
    int m = m0 + tid;
    tok[tid] = row_token[start + ((m < cnt) ? m : (cnt - 1))];
  }
  __syncthreads();

  int lane = tid & 63;
  int wave = tid >> 6;
  int quad = lane >> 4;
  int lrow = lane & 15;
  int wm = (wave >> 1) * 64;  // 0 / 64
  int wn = (wave & 1) * 32;   // 0 / 32

  // precomputed per-lane global staging addresses (k0 added per step)
  const unsigned short* gA[2];
#pragma unroll
  for (int j = 0; j < 2; j++) {
    int s = (wave * 2 + j) * 64 + lane;  // slot in [0,512): m = s>>2, c = s&3
    gA[j] = xb + (size_t)tok[s >> 2] * H + (s & 3) * 8;
  }
  int sB = wave * 64 + lane;  // slot in [0,256): n = s>>2, c = s&3
  const unsigned short* gBg = Wg + (size_t)(n0 + (sB >> 2)) * H + (sB & 3) * 8;
  const unsigned short* gBu = gBg + (size_t)I * H;
  short* ldsA0 = &As[(wave * 2 + 0) * 64 * 8];
  short* ldsA1 = &As[(wave * 2 + 1) * 64 * 8];
  short* ldsBg = &Bg[wave * 64 * 8];
  short* ldsBu = &Bu[wave * 64 * 8];

  floatx4 accg[4][2], accu[4][2];
#pragma unroll
  for (int i = 0; i < 4; i++)
#pragma unroll
    for (int j = 0; j < 2; j++) {
      accg[i][j] = floatx4{0.f, 0.f, 0.f, 0.f};
      accu[i][j] = floatx4{0.f, 0.f, 0.f, 0.f};
    }

  for (int k0 = 0; k0 < H; k0 += 32) {
    g2l16(gA[0] + k0, ldsA0);
    g2l16(gA[1] + k0, ldsA1);
    g2l16(gBg + k0, ldsBg);
    g2l16(gBu + k0, ldsBu);
    __syncthreads();

    short8 a[4], bg[2], bu[2];
#pragma unroll
    for (int ti = 0; ti < 4; ti++)
      a[ti] = *(const short8*)(&As[(wm + ti * 16 + lrow) * 32 + quad * 8]);
#pragma unroll
    for (int tj = 0; tj < 2; tj++) {
      bg[tj] = *(const short8*)(&Bg[(wn + tj * 16 + lrow) * 32 + quad * 8]);
      bu[tj] = *(const short8*)(&Bu[(wn + tj * 16 + lrow) * 32 + quad * 8]);
    }
#pragma unroll
    for (int ti = 0; ti < 4; ti++)
#pragma unroll
      for (int tj = 0; tj < 2; tj++) {
        accg[ti][tj] = __builtin_amdgcn_mfma_f32_16x16x32_bf16(
            a[ti], bg[tj], accg[ti][tj], 0, 0, 0);
        accu[ti][tj] = __builtin_amdgcn_mfma_f32_16x16x32_bf16(
            a[ti], bu[tj], accu[ti][tj], 0, 0, 0);
      }
    __syncthreads();
  }

#pragma unroll
  for (int ti = 0; ti < 4; ti++) {
#pragma unroll
    for (int tj = 0; tj < 2; tj++) {
      int ncol = n0 + wn + tj * 16 + lrow;
      float bgv = bias[ncol];
      float buv = bias[I + ncol];
#pragma unroll
      for (int r = 0; r < 4; r++) {
        int m = m0 + wm + ti * 16 + quad * 4 + r;
        if (m < cnt) {
          float g = accg[ti][tj][r] + bgv;
          float u = accu[ti][tj][r] + buv;
          g = fminf(g, LIMIT);
          u = fmaxf(fminf(u, LIMIT), -LIMIT);
          float glu = g / (1.0f + __expf(-ALPHA * g));
          act[(size_t)(start + m) * I + ncol] = f2bf((u + 1.0f) * glu);
        }
      }
    }
  }
}

// ---------------------------------------------------------------------------
// GEMM2 (MFMA + global_load_lds): down = act @ Wd[e] (+bd), weighted atomic
// scatter to out. 128m x 64n, K=768, BK=32.
// ---------------------------------------------------------------------------
__global__ __launch_bounds__(256) void gemm_down_mfma(
    const unsigned short* __restrict__ act, const unsigned short* __restrict__ Wdt,
    const float* __restrict__ bd, const int* __restrict__ e_start,
    const int* __restrict__ e_count, const int* __restrict__ row_token,
    const float* __restrict__ row_w, float* __restrict__ out) {
  int e = blockIdx.z;
  int cnt = e_count[e];
  int m0 = blockIdx.y * 128;
  if (m0 >= cnt) return;
  int n0 = blockIdx.x * 64;
  int start = e_start[e];
  const unsigned short* Wd = Wdt + (size_t)e * H * I;  // [h][i]
  const float* bias = bd + (size_t)e * H;

  __shared__ short As[128 * 32];
  __shared__ short Bs[64 * 32];
  __shared__ int tok[128];
  __shared__ float wts[128];

  int tid = threadIdx.x;
  if (tid < 128) {
    int m = m0 + tid;
    int mm = (m < cnt) ? m : (cnt - 1);
    tok[tid] = row_token[start + mm];
    wts[tid] = row_w[start + mm];
  }
  __syncthreads();

  int lane = tid & 63;
  int wave = tid >> 6;
  int quad = lane >> 4;
  int lrow = lane & 15;
  int wm = (wave >> 1) * 64;
  int wn = (wave & 1) * 32;

  const unsigned short* gA[2];
#pragma unroll
  for (int j = 0; j < 2; j++) {
    int s = (wave * 2 + j) * 64 + lane;
    int m = s >> 2;
    int gm = m0 + m;
    int mm = (gm < cnt) ? gm : (cnt - 1);
    gA[j] = act + (size_t)(start + mm) * I + (s & 3) * 8;
  }
  int sB = wave * 64 + lane;
  const unsigned short* gB = Wd + (size_t)(n0 + (sB >> 2)) * I + (sB & 3) * 8;
  short* ldsA0 = &As[(wave * 2 + 0) * 64 * 8];
  short* ldsA1 = &As[(wave * 2 + 1) * 64 * 8];
  short* ldsB = &Bs[wave * 64 * 8];

  floatx4 acc[4][2];
#pragma unroll
  for (int i = 0; i < 4; i++)
#pragma unroll
    for (int j = 0; j < 2; j++) acc[i][j] = floatx4{0.f, 0.f, 0.f, 0.f};

  for (int k0 = 0; k0 < I; k0 += 32) {
    g2l16(gA[0] + k0, ldsA0);
    g2l16(gA[1] + k0, ldsA1);
    g2l16(gB + k0, ldsB);
    __syncthreads();

    short8 a[4], b[2];
#pragma unroll
    for (int ti = 0; ti < 4; ti++)
      a[ti] = *(const short8*)(&As[(wm + ti * 16 + lrow) * 32 + quad * 8]);
#pragma unroll
    for (int tj = 0; tj < 2; tj++)
      b[tj] = *(const short8*)(&Bs[(wn + tj * 16 + lrow) * 32 + quad * 8]);
#pragma unroll
    for (int ti = 0; ti < 4; ti++)
#pragma unroll
      for (int tj = 0; tj < 2; tj++)
        acc[ti][tj] = __builtin_amdgcn_mfma_f32_16x16x32_bf16(
            a[ti], b[tj], acc[ti][tj], 0, 0, 0);
    __syncthreads();
  }

#pragma unroll
  for (int ti = 0; ti < 4; ti++) {
#pragma unroll
    for (int tj = 0; tj < 2; tj++) {
      int ncol = n0 + wn + tj * 16 + lrow;
      float bdv = bias[ncol];
#pragma unroll
      for (int r = 0; r < 4; r++) {
        int ml = wm + ti * 16 + quad * 4 + r;
        int m = m0 + ml;
        if (m < cnt) {
          int t = tok[ml];
          float w = wts[ml];
          atomicAdd(&out[(size_t)t * H + ncol], w * (acc[ti][tj][r] + bdv));
        }
      }
    }
  }
}

// ---------------------------------------------------------------------------
extern "C" void kernel_launch(void* const* d_in, const int* in_sizes, int n_in,
                              void* d_out, int out_size, void* d_ws,
                              size_t ws_size, hipStream_t stream) {
  const float* x   = (const float*)d_in[0];
  const float* Wr  = (const float*)d_in[1];
  const float* br  = (const float*)d_in[2];
  const float* Wgu = (const float*)d_in[3];
  const float* bgu = (const float*)d_in[4];
  const float* Wd  = (const float*)d_in[5];
  const float* bd  = (const float*)d_in[6];
  float* out = (float*)d_out;

  // workspace layout (all chunks 16B-aligned)
  char* w = (char*)d_ws;
  int* topk_idx = (int*)w;   w += (size_t)T * 2 * sizeof(int);
  float* topk_w = (float*)w; w += (size_t)T * 2 * sizeof(float);
  int* e_start = (int*)w;    w += 16 * sizeof(int);
  int* e_count = (int*)w;    w += 16 * sizeof(int);
  int* row_token = (int*)w;  w += (size_t)NROWS * sizeof(int);
  float* row_w = (float*)w;  w += (size_t)NROWS * sizeof(float);
  unsigned short* xb  = (unsigned short*)w; w += (size_t)T * H * 2;         // 3.1 MB
  unsigned short* Wgt = (unsigned short*)w; w += (size_t)E * TWO_I * H * 2; // 18.9 MB
  unsigned short* Wdt = (unsigned short*)w; w += (size_t)E * H * I * 2;     // 9.4 MB
  unsigned short* act = (unsigned short*)w; w += (size_t)NROWS * I * 2;     // 6.3 MB

  hipMemsetAsync(d_out, 0, (size_t)out_size * sizeof(float), stream);

  router_kernel<<<T, 64, 0, stream>>>(x, Wr, br, topk_idx, topk_w, xb);
  build_assign<<<1, 256, 0, stream>>>(topk_idx, topk_w, e_start, e_count,
                                      row_token, row_w);
  transpose_bf16<<<dim3(TWO_I / 32, H / 32, E), 256, 0, stream>>>(Wgu, Wgt, H,
                                                                  TWO_I);
  transpose_bf16<<<dim3(H / 32, I / 32, E), 256, 0, stream>>>(Wd, Wdt, I, H);
  // max rows per expert = T = 2048 -> 16 m-tiles of 128
  gemm_gu_mfma<<<dim3(I / 64, 16, E), 256, 0, stream>>>(
      xb, Wgt, bgu, e_start, e_count, row_token, act);
  gemm_down_mfma<<<dim3(H / 64, 16, E), 256, 0, stream>>>(
      act, Wdt, bd, e_start, e_count, row_token, row_w, out);
}